// Round 5
// baseline (136.623 us; speedup 1.0000x reference)
//
#include <hip/hip_runtime.h>
#include <hip/hip_bf16.h>
#include <stdint.h>

typedef __attribute__((ext_vector_type(8))) short bf16x8;
typedef __attribute__((ext_vector_type(4))) float f32x4;

#define T_TOKENS 8192
#define DIM 1024
#define ODIM 1024
#define NEXP 8

__device__ __forceinline__ unsigned short f2bf(float f) {
  unsigned u = __float_as_uint(f);
  u = (u + 0x7FFFu + ((u >> 16) & 1u)) >> 16;
  return (unsigned short)u;
}
__device__ __forceinline__ float bf2f(unsigned short h) {
  return __uint_as_float(((unsigned)h) << 16);
}

// ---------------- fused: expert_w fp32->bf16 convert (blocks 0..8191) + router (blocks 8192..10239) ----------------
__global__ __launch_bounds__(256) void prep_kernel(
    const float* __restrict__ ew, unsigned short* __restrict__ w_bf,
    const float* __restrict__ x, const float* __restrict__ gw, const float* __restrict__ gb,
    float* __restrict__ logits_out, unsigned short* __restrict__ x_bf,
    int* __restrict__ tk_e, float* __restrict__ tk_w) {
  if (blockIdx.x < 8192) {
    int i = blockIdx.x * 256 + threadIdx.x;  // 2M float4s
    float4 v = ((const float4*)ew)[i];
    ushort4 o;
    o.x = f2bf(v.x); o.y = f2bf(v.y); o.z = f2bf(v.z); o.w = f2bf(v.w);
    ((ushort4*)w_bf)[i] = o;
    return;
  }
  int wave = threadIdx.x >> 6, lane = threadIdx.x & 63;
  int t = (blockIdx.x - 8192) * 4 + wave;
  float acc[NEXP];
#pragma unroll
  for (int e = 0; e < NEXP; ++e) acc[e] = 0.f;
  const float4* xr = (const float4*)(x + (size_t)t * DIM);
  ushort4* xw = (ushort4*)(x_bf + (size_t)t * DIM);
#pragma unroll
  for (int it = 0; it < 4; ++it) {
    int d4 = it * 64 + lane;
    float4 xv = xr[d4];
    ushort4 xb;
    xb.x = f2bf(xv.x); xb.y = f2bf(xv.y); xb.z = f2bf(xv.z); xb.w = f2bf(xv.w);
    xw[d4] = xb;
#pragma unroll
    for (int e = 0; e < NEXP; ++e) {
      float4 gv = ((const float4*)(gw + e * DIM))[d4];
      acc[e] += xv.x * gv.x + xv.y * gv.y + xv.z * gv.z + xv.w * gv.w;
    }
  }
#pragma unroll
  for (int off = 32; off; off >>= 1)
#pragma unroll
    for (int e = 0; e < NEXP; ++e) acc[e] += __shfl_xor(acc[e], off);
  if (lane == 0) {
#pragma unroll
    for (int e = 0; e < NEXP; ++e) acc[e] += gb[e];
    float4 lo = make_float4(acc[0], acc[1], acc[2], acc[3]);
    float4 hi = make_float4(acc[4], acc[5], acc[6], acc[7]);
    float4* lp = (float4*)(logits_out + (size_t)t * NEXP);
    lp[0] = lo; lp[1] = hi;
    int e0 = 0; float l0 = acc[0];
#pragma unroll
    for (int e = 1; e < NEXP; ++e) if (acc[e] > l0) { l0 = acc[e]; e0 = e; }
    int e1 = -1; float l1 = -1e30f;
#pragma unroll
    for (int e = 0; e < NEXP; ++e) if (e != e0 && acc[e] > l1) { l1 = acc[e]; e1 = e; }
    float r = expf(l1 - l0);          // p1/p0
    float w0 = 1.f / (1.f + r);
    float w1 = r * w0;
    tk_e[t * 2] = e0; tk_e[t * 2 + 1] = e1;
    tk_w[t * 2] = w0; tk_w[t * 2 + 1] = w1;
  }
}

// ---------------- sort: deterministic counting-sort of 16384 (token,k) pairs by expert.
// Emits tile list (BM=256 x BN=128): entry = e | (nt<<4) | (mt<<8). Zeroes the pop counter.
__global__ __launch_bounds__(1024) void sort_kernel(
    const int* __restrict__ tk_e, const float* __restrict__ tk_w,
    int* __restrict__ offsets_g, int* __restrict__ row_token,
    float* __restrict__ row_weight, int* __restrict__ tk_pos,
    int* __restrict__ tiles_g, int* __restrict__ n_tiles_g) {
  int tid = threadIdx.x;
  int lane = tid & 63, wv = tid >> 6;  // 16 waves
  __shared__ int wavetot[16][NEXP];    // then reused as wave exclusive base
  __shared__ int offs_l[NEXP + 1];

  int pe[16];
  float tw[16];
  const int base = tid * 16;
#pragma unroll
  for (int i = 0; i < 4; ++i) {
    int4 v = ((const int4*)(tk_e + base))[i];
    pe[i * 4 + 0] = v.x; pe[i * 4 + 1] = v.y; pe[i * 4 + 2] = v.z; pe[i * 4 + 3] = v.w;
    float4 w = ((const float4*)(tk_w + base))[i];
    tw[i * 4 + 0] = w.x; tw[i * 4 + 1] = w.y; tw[i * 4 + 2] = w.z; tw[i * 4 + 3] = w.w;
  }
  int h[NEXP];
#pragma unroll
  for (int e = 0; e < NEXP; ++e) h[e] = 0;
#pragma unroll
  for (int i = 0; i < 16; ++i)
#pragma unroll
    for (int e = 0; e < NEXP; ++e) h[e] += (pe[i] == e);

  int incl[NEXP];
#pragma unroll
  for (int e = 0; e < NEXP; ++e) incl[e] = h[e];
#pragma unroll
  for (int off = 1; off < 64; off <<= 1) {
#pragma unroll
    for (int e = 0; e < NEXP; ++e) {
      int n = __shfl_up(incl[e], off);
      if (lane >= off) incl[e] += n;
    }
  }
  if (lane == 63)
#pragma unroll
    for (int e = 0; e < NEXP; ++e) wavetot[wv][e] = incl[e];
  __syncthreads();
  if (tid == 0) {
    int tot[NEXP];
#pragma unroll
    for (int e = 0; e < NEXP; ++e) tot[e] = 0;
    for (int w = 0; w < 16; ++w)
#pragma unroll
      for (int e = 0; e < NEXP; ++e) {
        int v = wavetot[w][e];
        wavetot[w][e] = tot[e];  // exclusive base per wave
        tot[e] += v;
      }
    int o = 0;
#pragma unroll
    for (int e = 0; e < NEXP; ++e) { offs_l[e] = o; o += tot[e]; }
    offs_l[NEXP] = o;
    for (int e = 0; e <= NEXP; ++e) offsets_g[e] = offs_l[e];
    // tile list: expert-major, m-tile(256 rows) major, n-tile(128 cols) fast
    int nb = 0;
    for (int e = 0; e < NEXP; ++e) {
      int mt = (tot[e] + 255) >> 8;
      for (int m = 0; m < mt; ++m)
        for (int n = 0; n < 8; ++n) tiles_g[nb++] = e | (n << 4) | (m << 8);
    }
    n_tiles_g[0] = nb;
    n_tiles_g[1] = 0;  // pop counter (re-zeroed every launch)
  }
  __syncthreads();

  int mybase[NEXP];
#pragma unroll
  for (int e = 0; e < NEXP; ++e) mybase[e] = offs_l[e] + wavetot[wv][e] + (incl[e] - h[e]);
  int run[NEXP];
#pragma unroll
  for (int e = 0; e < NEXP; ++e) run[e] = 0;
#pragma unroll
  for (int i = 0; i < 16; ++i) {
    int pos = 0;
#pragma unroll
    for (int e = 0; e < NEXP; ++e)
      if (pe[i] == e) { pos = mybase[e] + run[e]; run[e]++; }
    int pair = base + i;
    row_token[pos] = pair >> 1;
    row_weight[pos] = tw[i];
    tk_pos[pair] = pos;
  }
}

// ---------------- grouped GEMM: persistent blocks, 256x128 tile, BK=64, 8 waves (4M x 2N),
// triple-buffered LDS (3 x 48KB), counted vmcnt(6) per K-tile, 2 phases/K-tile.
#define GLOAD16(g, l)                                                                   \
  __builtin_amdgcn_global_load_lds((const __attribute__((address_space(1))) unsigned int*)(g), \
                                   (__attribute__((address_space(3))) unsigned int*)(l), 16, 0, 0)
#define BUFSZ 49152

__global__ __launch_bounds__(512, 2) void gemm_kernel(
    const unsigned short* __restrict__ x_bf, const unsigned short* __restrict__ w_bf,
    const int* __restrict__ row_token, const float* __restrict__ row_weight,
    const int* __restrict__ offsets, const int* __restrict__ tiles,
    int* __restrict__ n_tiles, unsigned short* __restrict__ tmp) {
  __shared__ __align__(16) char smem[3 * BUFSZ];  // per buf: A[256][64]bf16 @0, B[128][64]bf16 @32768
  __shared__ int sh_idx;
  const int nb = n_tiles[0];
  const int tid = threadIdx.x;
  const int lane = tid & 63, wave = tid >> 6;
  const int wr = wave >> 1, wc = wave & 1;  // 4M x 2N; wave output 64x64

  // fragment LDS offsets (buffer-relative), XOR-swizzled
  int aoff[4][2], boff[4][2];
  {
    const int kx = (lane >> 4) << 4;
    const int sw = (lane & 7) << 4;
#pragma unroll
    for (int m = 0; m < 4; ++m)
#pragma unroll
      for (int ks = 0; ks < 2; ++ks)
        aoff[m][ks] = (wr * 64 + m * 16 + (lane & 15)) * 128 + ((ks * 64 + kx) ^ sw);
#pragma unroll
    for (int n = 0; n < 4; ++n)
#pragma unroll
      for (int ks = 0; ks < 2; ++ks)
        boff[n][ks] = 32768 + (wc * 64 + n * 16 + (lane & 15)) * 128 + ((ks * 64 + kx) ^ sw);
  }
  // staging: issue = 64 rows x 128B; thread -> row srow, 16B chunk; src col pre-swizzled
  const int srow = tid >> 3;
  const int scol = ((tid & 7) ^ (srow & 7)) << 4;
  const int sdst = (tid & 7) << 4;

  for (;;) {
    if (tid == 0) sh_idx = atomicAdd(&n_tiles[1], 1);
    __syncthreads();
    const int idx = sh_idx;
    if (idx >= nb) return;
    const int s = tiles[idx];
    const int e = s & 7;
    const int n0 = ((s >> 4) & 15) << 7;
    const int m0 = (s >> 8) << 8;
    const int seg0 = offsets[e], segN = offsets[e + 1] - seg0;

    const char* srcA[4]; int dstA[4];
    const char* srcB[2]; int dstB[2];
#pragma unroll
    for (int i = 0; i < 4; ++i) {
      int row = i * 64 + srow;
      int gr = m0 + row; if (gr > segN - 1) gr = segN - 1;
      srcA[i] = (const char*)x_bf + (size_t)row_token[seg0 + gr] * 2048 + scol;
      dstA[i] = row * 128 + sdst;
    }
#pragma unroll
    for (int i = 0; i < 2; ++i) {
      int row = i * 64 + srow;
      srcB[i] = (const char*)w_bf + (((size_t)e << 20) + (size_t)(n0 + row) * 1024) * 2 + scol;
      dstB[i] = 32768 + row * 128 + sdst;
    }

    f32x4 acc[4][4];
#pragma unroll
    for (int m = 0; m < 4; ++m)
#pragma unroll
      for (int n = 0; n < 4; ++n) acc[m][n] = (f32x4){0.f, 0.f, 0.f, 0.f};

#define STAGE6(bufo, kb)                                  \
  {                                                       \
    GLOAD16(srcA[0] + (kb), smem + (bufo) + dstA[0]);     \
    GLOAD16(srcA[1] + (kb), smem + (bufo) + dstA[1]);     \
    GLOAD16(srcA[2] + (kb), smem + (bufo) + dstA[2]);     \
    GLOAD16(srcA[3] + (kb), smem + (bufo) + dstA[3]);     \
    GLOAD16(srcB[0] + (kb), smem + (bufo) + dstB[0]);     \
    GLOAD16(srcB[1] + (kb), smem + (bufo) + dstB[1]);     \
  }

    // prologue: kt0 -> buf0, kt1 -> buf1 (12 loads in flight)
    STAGE6(0, 0);
    STAGE6(BUFSZ, 128);

    int cb = 0;
    for (int kt = 0; kt < 15; ++kt) {
      // retire tile kt's 6 loads; keep kt+1's 6 in flight. NEVER drain to 0 here.
      asm volatile("s_waitcnt vmcnt(6)" ::: "memory");
      __builtin_amdgcn_s_barrier();
      const char* cur = smem + cb * BUFSZ;
      int cbn = cb + 2; if (cbn >= 3) cbn -= 3;
      char* nx = smem + cbn * BUFSZ;
      const int kb2 = (kt + 2) * 128;
      const bool iss = kt < 14;

      // ---- phase 0 (ks=0): 8 ds_read + 3 prefetch gloads + 16 MFMA ----
      {
        bf16x8 a_[4], b_[4];
#pragma unroll
        for (int m = 0; m < 4; ++m) a_[m] = *(const bf16x8*)(cur + aoff[m][0]);
#pragma unroll
        for (int n = 0; n < 4; ++n) b_[n] = *(const bf16x8*)(cur + boff[n][0]);
        if (iss) {
          GLOAD16(srcA[0] + kb2, nx + dstA[0]);
          GLOAD16(srcA[1] + kb2, nx + dstA[1]);
          GLOAD16(srcB[0] + kb2, nx + dstB[0]);
        }
        __builtin_amdgcn_s_barrier();
        __builtin_amdgcn_s_setprio(1);
#pragma unroll
        for (int m = 0; m < 4; ++m)
#pragma unroll
          for (int n = 0; n < 4; ++n)
            acc[m][n] = __builtin_amdgcn_mfma_f32_16x16x32_bf16(a_[m], b_[n], acc[m][n], 0, 0, 0);
        __builtin_amdgcn_s_setprio(0);
        __builtin_amdgcn_s_barrier();
      }
      // ---- phase 1 (ks=1) ----
      {
        bf16x8 a_[4], b_[4];
#pragma unroll
        for (int m = 0; m < 4; ++m) a_[m] = *(const bf16x8*)(cur + aoff[m][1]);
#pragma unroll
        for (int n = 0; n < 4; ++n) b_[n] = *(const bf16x8*)(cur + boff[n][1]);
        if (iss) {
          GLOAD16(srcA[2] + kb2, nx + dstA[2]);
          GLOAD16(srcA[3] + kb2, nx + dstA[3]);
          GLOAD16(srcB[1] + kb2, nx + dstB[1]);
        }
        __builtin_amdgcn_s_barrier();
        __builtin_amdgcn_s_setprio(1);
#pragma unroll
        for (int m = 0; m < 4; ++m)
#pragma unroll
          for (int n = 0; n < 4; ++n)
            acc[m][n] = __builtin_amdgcn_mfma_f32_16x16x32_bf16(a_[m], b_[n], acc[m][n], 0, 0, 0);
        __builtin_amdgcn_s_setprio(0);
        __builtin_amdgcn_s_barrier();
      }
      cb = (cb + 1 == 3) ? 0 : cb + 1;
    }
    // ---- final K-tile (kt=15): full drain, no prefetch ----
    {
      asm volatile("s_waitcnt vmcnt(0)" ::: "memory");
      __builtin_amdgcn_s_barrier();
      const char* cur = smem + cb * BUFSZ;
#pragma unroll
      for (int ks = 0; ks < 2; ++ks) {
        bf16x8 a_[4], b_[4];
#pragma unroll
        for (int m = 0; m < 4; ++m) a_[m] = *(const bf16x8*)(cur + aoff[m][ks]);
#pragma unroll
        for (int n = 0; n < 4; ++n) b_[n] = *(const bf16x8*)(cur + boff[n][ks]);
#pragma unroll
        for (int m = 0; m < 4; ++m)
#pragma unroll
          for (int n = 0; n < 4; ++n)
            acc[m][n] = __builtin_amdgcn_mfma_f32_16x16x32_bf16(a_[m], b_[n], acc[m][n], 0, 0, 0);
      }
    }

    // ---- epilogue: scale by routing weight, store bf16 ----
#pragma unroll
    for (int m = 0; m < 4; ++m) {
#pragma unroll
      for (int r = 0; r < 4; ++r) {
        int gr = m0 + wr * 64 + m * 16 + ((lane >> 4) << 2) + r;
        if (gr < segN) {
          int p = seg0 + gr;
          float w = row_weight[p];
#pragma unroll
          for (int n = 0; n < 4; ++n) {
            int col = n0 + wc * 64 + n * 16 + (lane & 15);
            tmp[(size_t)p * 1024 + col] = f2bf(acc[m][n][r] * w);
          }
        }
      }
    }
#undef STAGE6
  }
}

// ---------------- combine: out[t] = tmp[p0] + tmp[p1] + w0*b[e0] + w1*b[e1] ----------------
__global__ __launch_bounds__(256) void combine_kernel(
    const unsigned short* __restrict__ tmp, const float* __restrict__ eb,
    const int* __restrict__ tk_e, const float* __restrict__ tk_w,
    const int* __restrict__ tk_pos, float* __restrict__ out) {
  int t = blockIdx.x;
  int o = threadIdx.x * 4;
  int p0 = tk_pos[t * 2], p1 = tk_pos[t * 2 + 1];
  int e0 = tk_e[t * 2], e1 = tk_e[t * 2 + 1];
  float w0 = tk_w[t * 2], w1 = tk_w[t * 2 + 1];
  ushort4 a = *(const ushort4*)(tmp + (size_t)p0 * 1024 + o);
  ushort4 b = *(const ushort4*)(tmp + (size_t)p1 * 1024 + o);
  float4 b0 = *(const float4*)(eb + e0 * 1024 + o);
  float4 b1 = *(const float4*)(eb + e1 * 1024 + o);
  float4 r;
  r.x = bf2f(a.x) + bf2f(b.x) + w0 * b0.x + w1 * b1.x;
  r.y = bf2f(a.y) + bf2f(b.y) + w0 * b0.y + w1 * b1.y;
  r.z = bf2f(a.z) + bf2f(b.z) + w0 * b0.z + w1 * b1.z;
  r.w = bf2f(a.w) + bf2f(b.w) + w0 * b0.w + w1 * b1.w;
  *(float4*)(out + (size_t)t * 1024 + o) = r;
}

extern "C" void kernel_launch(void* const* d_in, const int* in_sizes, int n_in,
                              void* d_out, int out_size, void* d_ws, size_t ws_size,
                              hipStream_t stream) {
  const float* x  = (const float*)d_in[0];
  const float* gw = (const float*)d_in[1];
  const float* gb = (const float*)d_in[2];
  const float* ew = (const float*)d_in[3];
  const float* eb = (const float*)d_in[4];
  float* out = (float*)d_out;
  float* logits = out + (size_t)T_TOKENS * ODIM;

  char* ws = (char*)d_ws;
  unsigned short* x_bf = (unsigned short*)(ws);                 // 16 MB
  unsigned short* w_bf = (unsigned short*)(ws + 16777216);      // 16 MB
  unsigned short* tmp  = (unsigned short*)(ws + 33554432);      // 32 MB
  int*   tk_e      = (int*)(ws + 67108864);
  float* tk_w      = (float*)(ws + 67174400);
  int*   tk_pos    = (int*)(ws + 67239936);
  int*   row_token = (int*)(ws + 67305472);
  float* row_weight= (float*)(ws + 67371008);
  int*   offsets   = (int*)(ws + 67436544);  // 9 ints
  int*   n_tiles   = (int*)(ws + 67436608);  // [0]=nb, [1]=pop counter
  int*   tiles     = (int*)(ws + 67436672);  // up to 1024 ints

  prep_kernel<<<10240, 256, 0, stream>>>(ew, w_bf, x, gw, gb, logits, x_bf, tk_e, tk_w);
  sort_kernel<<<1, 1024, 0, stream>>>(tk_e, tk_w, offsets, row_token, row_weight, tk_pos,
                                      tiles, n_tiles);
  gemm_kernel<<<256, 512, 0, stream>>>(x_bf, w_bf, row_token, row_weight, offsets, tiles,
                                       n_tiles, tmp);
  combine_kernel<<<8192, 256, 0, stream>>>(tmp, eb, tk_e, tk_w, tk_pos, out);
}